// Round 14
// baseline (140.665 us; speedup 1.0000x reference)
//
#include <hip/hip_runtime.h>
#include <hip/hip_bf16.h>

#define INC   256
#define HEADS 4
#define OUTC  64
#define NEG_SLOPE 0.2f
#define CAP   5120      // per-bucket edge capacity (lambda=4096, +16 sigma)
#define EPB_A 4096      // edges per pass-A block

typedef __attribute__((ext_vector_type(8))) short  fragA;  // 8 bf16 in 4 VGPRs
typedef __attribute__((ext_vector_type(4))) float  f32x4;

__device__ __forceinline__ float bf2f(unsigned short u) {
    union { unsigned int i; float f; } v; v.i = ((unsigned int)u) << 16; return v.f;
}
__device__ __forceinline__ unsigned short f2bf(float x) {
    __hip_bfloat16 b = __float2bfloat16(x);
    return *reinterpret_cast<unsigned short*>(&b);
}

// ------- Wt = bf16(W^T) [256 n][256 k]; zero bucket tails + degree totals -------
__global__ __launch_bounds__(256) void wt_zero_kernel(const float* __restrict__ W,
                                                      unsigned short* __restrict__ Wt,
                                                      int* __restrict__ btail, int nbuck,
                                                      int* __restrict__ dtotal)
{
    int idx = blockIdx.x * 256 + threadIdx.x;   // 0..65535
    int k = idx >> 8, c = idx & 255;
    Wt[c * 256 + k] = f2bf(W[k * 256 + c]);
    if (idx < nbuck) btail[idx] = 0;
    if (idx < 64)    dtotal[idx] = 0;
}

// ---------------- heterogeneous: pass-A bucket scatter (blocks < nbA) + GEMM ----------------
__global__ __launch_bounds__(256, 2) void gemm_passA(
    const float* __restrict__ A,            // [M,256] f32
    const unsigned short* __restrict__ Wt,  // [256 n][256 k] bf16
    const float* __restrict__ att_src,      // [4,64]
    const float* __restrict__ att_dst,      // [4,64]
    unsigned short* __restrict__ H2,        // [M,256] bf16
    float* __restrict__ a_srcO,             // [M,4]
    float* __restrict__ a_dstO,             // [M,4]
    int M,
    const int* __restrict__ src, const int* __restrict__ dst,
    int* __restrict__ btail,                // [nbuck]
    int2* __restrict__ bucketbuf,           // [nbuck*CAP]
    int E, int nbA)
{
    __shared__ __align__(16) unsigned short As[64 * 256];   // 32 KB (pass A reuses)
    const int tid = threadIdx.x;

    if ((int)blockIdx.x < nbA) {
        // ---------------- pass A: bin edges by dst>>8 ----------------
        char* sm = (char*)As;
        int* lhist = (int*)sm;            // 256 ints
        int* lrankc = (int*)(sm + 1024);  // 256 ints
        int* gbase  = (int*)(sm + 2048);  // 256 ints
        lhist[tid] = 0; lrankc[tid] = 0;
        __syncthreads();
        int e0 = blockIdx.x * EPB_A;
        int e1 = e0 + EPB_A; if (e1 > E) e1 = E;
        for (int e = e0 + tid; e < e1; e += 256)
            atomicAdd(&lhist[dst[e] >> 8], 1);
        __syncthreads();
        {
            int c = lhist[tid];
            gbase[tid] = (c > 0) ? atomicAdd(&btail[tid], c) : 0;
        }
        __syncthreads();
        for (int e = e0 + tid; e < e1; e += 256) {
            int s = src[e], d = dst[e];
            int b = d >> 8;
            int r = atomicAdd(&lrankc[b], 1);
            bucketbuf[(size_t)b * CAP + gbase[b] + r] = make_int2(s, d);
        }
        return;
    }

    // ---------------- GEMM blocks ----------------
    const int lane = tid & 63;
    const int wave = tid >> 6;
    const int row0 = ((int)blockIdx.x - nbA) * 64;
    const int g   = lane >> 4;
    const int r16 = lane & 15;

    fragA b[4][8];
    {
        const unsigned short* wp = Wt + (size_t)(wave * 64) * 256;
        #pragma unroll
        for (int nn = 0; nn < 4; ++nn)
            #pragma unroll
            for (int kk = 0; kk < 8; ++kk)
                b[nn][kk] = *(const fragA*)(wp + (size_t)(nn * 16 + r16) * 256 + kk * 32 + g * 8);
    }

    #pragma unroll
    for (int i = 0; i < 16; ++i) {
        int f   = i * 256 + tid;
        int row = f >> 6;
        int q   = f & 63;
        int gr  = row0 + row;
        float4 v = (gr < M) ? *(const float4*)(A + (size_t)gr * INC + q * 4)
                            : make_float4(0.f, 0.f, 0.f, 0.f);
        ushort4 u;
        u.x = f2bf(v.x); u.y = f2bf(v.y); u.z = f2bf(v.z); u.w = f2bf(v.w);
        int byte = (row << 9) + (q << 3);
        byte ^= (row & 7) << 4;
        *(ushort4*)((char*)As + byte) = u;
    }
    __syncthreads();

    f32x4 acc[4][4] = {};
    #pragma unroll
    for (int kk = 0; kk < 8; ++kk) {
        fragA a[4];
        #pragma unroll
        for (int m = 0; m < 4; ++m) {
            int row  = m * 16 + r16;
            int byte = (row << 9) + ((kk * 32 + g * 8) << 1);
            byte ^= (row & 7) << 4;
            a[m] = *(const fragA*)((const char*)As + byte);
        }
        #pragma unroll
        for (int m = 0; m < 4; ++m)
            #pragma unroll
            for (int nn = 0; nn < 4; ++nn)
                acc[m][nn] = __builtin_amdgcn_mfma_f32_16x16x32_bf16(
                    a[m], b[nn][kk], acc[m][nn], 0, 0, 0);
    }

    #pragma unroll
    for (int m = 0; m < 4; ++m) {
        #pragma unroll
        for (int nn = 0; nn < 4; ++nn) {
            int gcol = wave * 64 + nn * 16 + r16;
            #pragma unroll
            for (int r = 0; r < 4; ++r) {
                int grow = row0 + m * 16 + g * 4 + r;
                if (grow < M)
                    H2[(size_t)grow * (HEADS * OUTC) + gcol] = f2bf(acc[m][nn][r]);
            }
        }
    }

    {
        float as_att[4], ad_att[4];
        #pragma unroll
        for (int nn = 0; nn < 4; ++nn) {
            as_att[nn] = att_src[wave * 64 + nn * 16 + r16];
            ad_att[nn] = att_dst[wave * 64 + nn * 16 + r16];
        }
        float sv[4][4], dv[4][4];
        #pragma unroll
        for (int m = 0; m < 4; ++m)
            #pragma unroll
            for (int r = 0; r < 4; ++r) {
                float s = 0.f, d = 0.f;
                #pragma unroll
                for (int nn = 0; nn < 4; ++nn) {
                    s = fmaf(acc[m][nn][r], as_att[nn], s);
                    d = fmaf(acc[m][nn][r], ad_att[nn], d);
                }
                sv[m][r] = s; dv[m][r] = d;
            }
        #pragma unroll
        for (int off = 1; off < 16; off <<= 1) {
            #pragma unroll
            for (int m = 0; m < 4; ++m)
                #pragma unroll
                for (int r = 0; r < 4; ++r) {
                    sv[m][r] += __shfl_xor(sv[m][r], off, 64);
                    dv[m][r] += __shfl_xor(dv[m][r], off, 64);
                }
        }
        #pragma unroll
        for (int m = 0; m < 4; ++m)
            #pragma unroll
            for (int r = 0; r < 4; ++r) {
                if (r16 == m * 4 + r) {
                    int grow = row0 + m * 16 + g * 4 + r;
                    if (grow < M) {
                        a_srcO[(size_t)grow * HEADS + wave] = sv[m][r];
                        a_dstO[(size_t)grow * HEADS + wave] = dv[m][r];
                    }
                }
            }
    }
}

// ---------------- pass B: in-bucket counting sort -> CSR esrc + offsets ----------------
__global__ __launch_bounds__(256) void passB_kernel(const int2* __restrict__ bucketbuf,
                                                    const int* __restrict__ btail,
                                                    int* __restrict__ offsets,
                                                    int* __restrict__ esrc,
                                                    int N, int E)
{
    __shared__ int lcnt[256];
    __shared__ int red[256];
    __shared__ unsigned short lrank[CAP];
    const int b = blockIdx.x, t = threadIdx.x;

    int s0 = 0;
    for (int j = t; j < b; j += 256) s0 += btail[j];
    red[t] = s0;
    __syncthreads();
    for (int off = 128; off > 0; off >>= 1) {
        if (t < off) red[t] += red[t + off];
        __syncthreads();
    }
    const int baseg = red[0];
    const int cnt = btail[b];
    __syncthreads();

    lcnt[t] = 0;
    __syncthreads();
    const int2* bb = bucketbuf + (size_t)b * CAP;
    for (int i = t; i < cnt; i += 256)
        lrank[i] = (unsigned short)atomicAdd(&lcnt[bb[i].y & 255], 1);
    __syncthreads();

    int v = lcnt[t];
    red[t] = v;
    __syncthreads();
    for (int off = 1; off < 256; off <<= 1) {
        int x = (t >= off) ? red[t - off] : 0;
        __syncthreads();
        red[t] += x;
        __syncthreads();
    }
    int excl = red[t] - v;
    lcnt[t] = excl;
    int node = b * 256 + t;
    if (node < N) offsets[node] = baseg + excl;
    if (b == 0 && t == 0) offsets[N] = E;
    __syncthreads();

    for (int i = t; i < cnt; i += 256) {
        int2 sd = bb[i];
        int slot = baseg + lcnt[sd.y & 255] + lrank[i];
        esrc[slot] = sd.x;
    }
}

// ---------------- degree sort, phase 1: per-block hist; blockbase = return-atomic ----
__global__ __launch_bounds__(256) void dsort1_kernel(const int* __restrict__ offsets,
                                                     int* __restrict__ dtotal,     // [64]
                                                     int* __restrict__ blockbase,  // [nb*64]
                                                     int N)
{
    __shared__ int lh[64];
    const int t = threadIdx.x, b = blockIdx.x;
    const int i = b * 256 + t;
    if (t < 64) lh[t] = 0;
    __syncthreads();
    if (i < N) {
        int deg = offsets[i + 1] - offsets[i];
        if (deg > 63) deg = 63;
        atomicAdd(&lh[deg], 1);
    }
    __syncthreads();
    if (t < 64) blockbase[b * 64 + t] = atomicAdd(&dtotal[t], lh[t]);
}

// ---------------- degree sort, phase 2: scan dtotal locally; place nodes ----------------
__global__ __launch_bounds__(256) void dsort2_kernel(const int* __restrict__ offsets,
                                                     const int* __restrict__ dtotal,
                                                     const int* __restrict__ blockbase,
                                                     int* __restrict__ perm,
                                                     int N)
{
    __shared__ int lr[64], dbase[64];
    const int t = threadIdx.x, b = blockIdx.x;
    const int i = b * 256 + t;
    if (t < 64) { lr[t] = 0; dbase[t] = dtotal[t]; }
    __syncthreads();
    if (t == 0) {
        int run = 0;
        #pragma unroll 1
        for (int d = 0; d < 64; ++d) { int c = dbase[d]; dbase[d] = run; run += c; }
    }
    __syncthreads();
    if (i < N) {
        int deg = offsets[i + 1] - offsets[i];
        if (deg > 63) deg = 63;
        int r = atomicAdd(&lr[deg], 1);
        perm[dbase[deg] + blockbase[b * 64 + deg] + r] = i;
    }
}

// ---------------- fused aggregation: wave per node (degree-sorted), lane = head*16+cg ----
// lean ILP-4 body, inline exp; TLP does the latency hiding.
__global__ __launch_bounds__(128) void fused_agg_kernel(
    const unsigned short* __restrict__ h2,      // [N,256] bf16
    const float* __restrict__ a_src,            // [N,4]
    const float* __restrict__ a_dst,            // [N,4]
    const int*   __restrict__ offsets,          // [N+1]
    const int*   __restrict__ esrc,             // [E]
    const int*   __restrict__ perm,             // [N] degree-grouped order
    const float* __restrict__ bias,             // [64]
    float*       __restrict__ out,              // [N,64]
    int n)
{
    int w    = (int)((blockIdx.x * blockDim.x + threadIdx.x) >> 6);
    int lane = threadIdx.x & 63;
    if (w >= n) return;
    const int i  = perm[w];
    const int h  = lane >> 4;
    const int cg = lane & 15;

    const float ad = a_dst[(size_t)i * HEADS + h];
    const unsigned short* h2p = h2 + lane * 4;

    float acc0, acc1, acc2, acc3, l;
    {   // self-loop
        float as = a_src[(size_t)i * HEADS + h];
        float e = as + ad; e = e > 0.f ? e : NEG_SLOPE * e;
        float p = __expf(e);
        ushort4 v = *(const ushort4*)(h2p + (size_t)i * 256);
        l = p;
        acc0 = p * bf2f(v.x);
        acc1 = p * bf2f(v.y);
        acc2 = p * bf2f(v.z);
        acc3 = p * bf2f(v.w);
    }

#define EDGE_BODY(S, AS)                                                     \
    {                                                                        \
        float e_ = (AS) + ad; e_ = e_ > 0.f ? e_ : NEG_SLOPE * e_;           \
        float p_ = __expf(e_);                                               \
        ushort4 v_ = *(const ushort4*)(h2p + (size_t)(S) * 256);             \
        l += p_;                                                             \
        acc0 = fmaf(p_, bf2f(v_.x), acc0);                                   \
        acc1 = fmaf(p_, bf2f(v_.y), acc1);                                   \
        acc2 = fmaf(p_, bf2f(v_.z), acc2);                                   \
        acc3 = fmaf(p_, bf2f(v_.w), acc3);                                   \
    }

    int beg = offsets[i], end = offsets[i + 1];
    int j = beg;
    // align to 4 for int4 esrc loads
    for (; j < end && (j & 3); ++j) {
        int s = esrc[j];
        float as = a_src[(size_t)s * HEADS + h];
        EDGE_BODY(s, as);
    }
    // batches of 4: one int4 load -> 4 a_src + 4 h2 gathers in flight
    for (; j + 3 < end; j += 4) {
        int4 ea = *(const int4*)(esrc + j);
        float as0 = a_src[(size_t)ea.x * HEADS + h];
        float as1 = a_src[(size_t)ea.y * HEADS + h];
        float as2 = a_src[(size_t)ea.z * HEADS + h];
        float as3 = a_src[(size_t)ea.w * HEADS + h];
        ushort4 v0 = *(const ushort4*)(h2p + (size_t)ea.x * 256);
        ushort4 v1 = *(const ushort4*)(h2p + (size_t)ea.y * 256);
        ushort4 v2 = *(const ushort4*)(h2p + (size_t)ea.z * 256);
        ushort4 v3 = *(const ushort4*)(h2p + (size_t)ea.w * 256);
        float e0 = as0 + ad; e0 = e0 > 0.f ? e0 : NEG_SLOPE * e0; float p0 = __expf(e0);
        float e1 = as1 + ad; e1 = e1 > 0.f ? e1 : NEG_SLOPE * e1; float p1 = __expf(e1);
        float e2 = as2 + ad; e2 = e2 > 0.f ? e2 : NEG_SLOPE * e2; float p2 = __expf(e2);
        float e3 = as3 + ad; e3 = e3 > 0.f ? e3 : NEG_SLOPE * e3; float p3 = __expf(e3);
        l += (p0 + p1) + (p2 + p3);
        acc0 = fmaf(p0, bf2f(v0.x), acc0);
        acc1 = fmaf(p0, bf2f(v0.y), acc1);
        acc2 = fmaf(p0, bf2f(v0.z), acc2);
        acc3 = fmaf(p0, bf2f(v0.w), acc3);
        acc0 = fmaf(p1, bf2f(v1.x), acc0);
        acc1 = fmaf(p1, bf2f(v1.y), acc1);
        acc2 = fmaf(p1, bf2f(v1.z), acc2);
        acc3 = fmaf(p1, bf2f(v1.w), acc3);
        acc0 = fmaf(p2, bf2f(v2.x), acc0);
        acc1 = fmaf(p2, bf2f(v2.y), acc1);
        acc2 = fmaf(p2, bf2f(v2.z), acc2);
        acc3 = fmaf(p2, bf2f(v2.w), acc3);
        acc0 = fmaf(p3, bf2f(v3.x), acc0);
        acc1 = fmaf(p3, bf2f(v3.y), acc1);
        acc2 = fmaf(p3, bf2f(v3.z), acc2);
        acc3 = fmaf(p3, bf2f(v3.w), acc3);
    }
    for (; j < end; ++j) {
        int s = esrc[j];
        float as = a_src[(size_t)s * HEADS + h];
        EDGE_BODY(s, as);
    }
#undef EDGE_BODY

    float inv = 1.f / (l + 1e-16f);
    float r0 = acc0 * inv, r1 = acc1 * inv, r2 = acc2 * inv, r3 = acc3 * inv;

    r0 += __shfl_xor(r0, 16, 64); r0 += __shfl_xor(r0, 32, 64);
    r1 += __shfl_xor(r1, 16, 64); r1 += __shfl_xor(r1, 32, 64);
    r2 += __shfl_xor(r2, 16, 64); r2 += __shfl_xor(r2, 32, 64);
    r3 += __shfl_xor(r3, 16, 64); r3 += __shfl_xor(r3, 32, 64);

    if (lane < 16) {
        float4 b4 = *(const float4*)(bias + cg * 4);
        float4 o;
        o.x = 0.25f * r0 + b4.x;
        o.y = 0.25f * r1 + b4.y;
        o.z = 0.25f * r2 + b4.z;
        o.w = 0.25f * r3 + b4.w;
        *(float4*)(out + (size_t)i * OUTC + cg * 4) = o;
    }
}

extern "C" void kernel_launch(void* const* d_in, const int* in_sizes, int n_in,
                              void* d_out, int out_size, void* d_ws, size_t ws_size,
                              hipStream_t stream)
{
    (void)n_in; (void)out_size; (void)ws_size;
    const float* x       = (const float*)d_in[0];
    const int*   edge    = (const int*)d_in[1];
    const float* W       = (const float*)d_in[2];
    const float* att_src = (const float*)d_in[3];
    const float* att_dst = (const float*)d_in[4];
    const float* bias    = (const float*)d_in[5];
    float* out = (float*)d_out;

    const int N = in_sizes[0] / INC;
    const int E = in_sizes[1] / 2;
    const int* srcA = edge;
    const int* dstA = edge + E;
    const int nbuck = (N + 255) / 256;          // 196
    const int nbA   = (E + EPB_A - 1) / EPB_A;  // 196
    const int nbn   = (N + 255) / 256;          // node blocks

    char* ws = (char*)d_ws;
    unsigned short* h2 = (unsigned short*)ws; ws += (size_t)N * (HEADS * OUTC) * sizeof(unsigned short);
    unsigned short* Wt = (unsigned short*)ws; ws += (size_t)256 * 256 * sizeof(unsigned short);
    float* a_src  = (float*)ws; ws += (size_t)N * HEADS * sizeof(float);
    float* a_dst  = (float*)ws; ws += (size_t)N * HEADS * sizeof(float);
    int* offsets  = (int*)ws;   ws += (size_t)(N + 1) * sizeof(int) + 12;
    int* btail    = (int*)ws;   ws += (size_t)256 * sizeof(int);
    int* dtotal   = (int*)ws;   ws += (size_t)64 * sizeof(int);
    int* blockbase= (int*)ws;   ws += (size_t)nbn * 64 * sizeof(int);
    int* perm     = (int*)ws;   ws += (size_t)N * sizeof(int);
    int2* bucketbuf = (int2*)ws; ws += (size_t)nbuck * CAP * sizeof(int2);
    int* esrc     = (int*)ws;   ws += (size_t)E * sizeof(int);

    wt_zero_kernel<<<256, 256, 0, stream>>>(W, Wt, btail, nbuck, dtotal);

    gemm_passA<<<nbA + (N + 63) / 64, 256, 0, stream>>>(
        x, Wt, att_src, att_dst, h2, a_src, a_dst, N,
        srcA, dstA, btail, bucketbuf, E, nbA);

    passB_kernel<<<nbuck, 256, 0, stream>>>(bucketbuf, btail, offsets, esrc, N, E);

    dsort1_kernel<<<nbn, 256, 0, stream>>>(offsets, dtotal, blockbase, N);
    dsort2_kernel<<<nbn, 256, 0, stream>>>(offsets, dtotal, blockbase, perm, N);

    fused_agg_kernel<<<(N + 1) / 2, 128, 0, stream>>>(h2, a_src, a_dst, offsets, esrc,
                                                      perm, bias, out, N);
}

// Round 15
// 135.661 us; speedup vs baseline: 1.0369x; 1.0369x over previous
//
#include <hip/hip_runtime.h>
#include <hip/hip_bf16.h>

#define INC   256
#define HEADS 4
#define OUTC  64
#define NEG_SLOPE 0.2f
#define CAP   5120      // per-bucket edge capacity (lambda=4096, +16 sigma)
#define EPB_A 2048      // edges per pass-A block (smaller => passA hides under GEMM)

typedef __attribute__((ext_vector_type(8))) short  fragA;  // 8 bf16 in 4 VGPRs
typedef __attribute__((ext_vector_type(4))) float  f32x4;

__device__ __forceinline__ float bf2f(unsigned short u) {
    union { unsigned int i; float f; } v; v.i = ((unsigned int)u) << 16; return v.f;
}
__device__ __forceinline__ unsigned short f2bf(float x) {
    __hip_bfloat16 b = __float2bfloat16(x);
    return *reinterpret_cast<unsigned short*>(&b);
}

// ------- Wt = bf16(W^T) [256 n][256 k]; zero bucket tails -------
__global__ __launch_bounds__(256) void wt_zero_kernel(const float* __restrict__ W,
                                                      unsigned short* __restrict__ Wt,
                                                      int* __restrict__ btail, int nbuck)
{
    int idx = blockIdx.x * 256 + threadIdx.x;   // 0..65535
    int k = idx >> 8, c = idx & 255;
    Wt[c * 256 + k] = f2bf(W[k * 256 + c]);
    if (idx < nbuck) btail[idx] = 0;
}

// ---------------- heterogeneous: pass-A bucket scatter (blocks < nbA) + GEMM ----------------
__global__ __launch_bounds__(256, 2) void gemm_passA(
    const float* __restrict__ A,            // [M,256] f32
    const unsigned short* __restrict__ Wt,  // [256 n][256 k] bf16
    const float* __restrict__ att_src,      // [4,64]
    const float* __restrict__ att_dst,      // [4,64]
    unsigned short* __restrict__ H2,        // [M,256] bf16
    float* __restrict__ a_srcO,             // [M,4]
    float* __restrict__ a_dstO,             // [M,4]
    int M,
    const int* __restrict__ src, const int* __restrict__ dst,
    int* __restrict__ btail,                // [nbuck]
    int2* __restrict__ bucketbuf,           // [nbuck*CAP]
    int E, int nbA)
{
    __shared__ __align__(16) unsigned short As[64 * 256];   // 32 KB (pass A reuses)
    const int tid = threadIdx.x;

    if ((int)blockIdx.x < nbA) {
        // ---------------- pass A: bin edges by dst>>8 ----------------
        char* sm = (char*)As;
        int* lhist = (int*)sm;            // 256 ints
        int* lrankc = (int*)(sm + 1024);  // 256 ints
        int* gbase  = (int*)(sm + 2048);  // 256 ints
        lhist[tid] = 0; lrankc[tid] = 0;
        __syncthreads();
        int e0 = blockIdx.x * EPB_A;
        int e1 = e0 + EPB_A; if (e1 > E) e1 = E;
        for (int e = e0 + tid; e < e1; e += 256)
            atomicAdd(&lhist[dst[e] >> 8], 1);
        __syncthreads();
        {
            int c = lhist[tid];
            gbase[tid] = (c > 0) ? atomicAdd(&btail[tid], c) : 0;
        }
        __syncthreads();
        for (int e = e0 + tid; e < e1; e += 256) {
            int s = src[e], d = dst[e];
            int b = d >> 8;
            int r = atomicAdd(&lrankc[b], 1);
            bucketbuf[(size_t)b * CAP + gbase[b] + r] = make_int2(s, d);
        }
        return;
    }

    // ---------------- GEMM blocks ----------------
    const int lane = tid & 63;
    const int wave = tid >> 6;
    const int row0 = ((int)blockIdx.x - nbA) * 64;
    const int g   = lane >> 4;
    const int r16 = lane & 15;

    fragA b[4][8];
    {
        const unsigned short* wp = Wt + (size_t)(wave * 64) * 256;
        #pragma unroll
        for (int nn = 0; nn < 4; ++nn)
            #pragma unroll
            for (int kk = 0; kk < 8; ++kk)
                b[nn][kk] = *(const fragA*)(wp + (size_t)(nn * 16 + r16) * 256 + kk * 32 + g * 8);
    }

    #pragma unroll
    for (int i = 0; i < 16; ++i) {
        int f   = i * 256 + tid;
        int row = f >> 6;
        int q   = f & 63;
        int gr  = row0 + row;
        float4 v = (gr < M) ? *(const float4*)(A + (size_t)gr * INC + q * 4)
                            : make_float4(0.f, 0.f, 0.f, 0.f);
        ushort4 u;
        u.x = f2bf(v.x); u.y = f2bf(v.y); u.z = f2bf(v.z); u.w = f2bf(v.w);
        int byte = (row << 9) + (q << 3);
        byte ^= (row & 7) << 4;
        *(ushort4*)((char*)As + byte) = u;
    }
    __syncthreads();

    f32x4 acc[4][4] = {};
    #pragma unroll
    for (int kk = 0; kk < 8; ++kk) {
        fragA a[4];
        #pragma unroll
        for (int m = 0; m < 4; ++m) {
            int row  = m * 16 + r16;
            int byte = (row << 9) + ((kk * 32 + g * 8) << 1);
            byte ^= (row & 7) << 4;
            a[m] = *(const fragA*)((const char*)As + byte);
        }
        #pragma unroll
        for (int m = 0; m < 4; ++m)
            #pragma unroll
            for (int nn = 0; nn < 4; ++nn)
                acc[m][nn] = __builtin_amdgcn_mfma_f32_16x16x32_bf16(
                    a[m], b[nn][kk], acc[m][nn], 0, 0, 0);
    }

    #pragma unroll
    for (int m = 0; m < 4; ++m) {
        #pragma unroll
        for (int nn = 0; nn < 4; ++nn) {
            int gcol = wave * 64 + nn * 16 + r16;
            #pragma unroll
            for (int r = 0; r < 4; ++r) {
                int grow = row0 + m * 16 + g * 4 + r;
                if (grow < M)
                    H2[(size_t)grow * (HEADS * OUTC) + gcol] = f2bf(acc[m][nn][r]);
            }
        }
    }

    {
        float as_att[4], ad_att[4];
        #pragma unroll
        for (int nn = 0; nn < 4; ++nn) {
            as_att[nn] = att_src[wave * 64 + nn * 16 + r16];
            ad_att[nn] = att_dst[wave * 64 + nn * 16 + r16];
        }
        float sv[4][4], dv[4][4];
        #pragma unroll
        for (int m = 0; m < 4; ++m)
            #pragma unroll
            for (int r = 0; r < 4; ++r) {
                float s = 0.f, d = 0.f;
                #pragma unroll
                for (int nn = 0; nn < 4; ++nn) {
                    s = fmaf(acc[m][nn][r], as_att[nn], s);
                    d = fmaf(acc[m][nn][r], ad_att[nn], d);
                }
                sv[m][r] = s; dv[m][r] = d;
            }
        #pragma unroll
        for (int off = 1; off < 16; off <<= 1) {
            #pragma unroll
            for (int m = 0; m < 4; ++m)
                #pragma unroll
                for (int r = 0; r < 4; ++r) {
                    sv[m][r] += __shfl_xor(sv[m][r], off, 64);
                    dv[m][r] += __shfl_xor(dv[m][r], off, 64);
                }
        }
        #pragma unroll
        for (int m = 0; m < 4; ++m)
            #pragma unroll
            for (int r = 0; r < 4; ++r) {
                if (r16 == m * 4 + r) {
                    int grow = row0 + m * 16 + g * 4 + r;
                    if (grow < M) {
                        a_srcO[(size_t)grow * HEADS + wave] = sv[m][r];
                        a_dstO[(size_t)grow * HEADS + wave] = dv[m][r];
                    }
                }
            }
    }
}

// ---------------- pass B: in-bucket counting sort -> CSR esrc + offsets ----------------
__global__ __launch_bounds__(256) void passB_kernel(const int2* __restrict__ bucketbuf,
                                                    const int* __restrict__ btail,
                                                    int* __restrict__ offsets,
                                                    int* __restrict__ esrc,
                                                    int N, int E)
{
    __shared__ int lcnt[256];
    __shared__ int red[256];
    __shared__ unsigned short lrank[CAP];
    const int b = blockIdx.x, t = threadIdx.x;

    int s0 = 0;
    for (int j = t; j < b; j += 256) s0 += btail[j];
    red[t] = s0;
    __syncthreads();
    for (int off = 128; off > 0; off >>= 1) {
        if (t < off) red[t] += red[t + off];
        __syncthreads();
    }
    const int baseg = red[0];
    const int cnt = btail[b];
    __syncthreads();

    lcnt[t] = 0;
    __syncthreads();
    const int2* bb = bucketbuf + (size_t)b * CAP;
    for (int i = t; i < cnt; i += 256)
        lrank[i] = (unsigned short)atomicAdd(&lcnt[bb[i].y & 255], 1);
    __syncthreads();

    int v = lcnt[t];
    red[t] = v;
    __syncthreads();
    for (int off = 1; off < 256; off <<= 1) {
        int x = (t >= off) ? red[t - off] : 0;
        __syncthreads();
        red[t] += x;
        __syncthreads();
    }
    int excl = red[t] - v;
    lcnt[t] = excl;
    int node = b * 256 + t;
    if (node < N) offsets[node] = baseg + excl;
    if (b == 0 && t == 0) offsets[N] = E;
    __syncthreads();

    for (int i = t; i < cnt; i += 256) {
        int2 sd = bb[i];
        int slot = baseg + lcnt[sd.y & 255] + lrank[i];
        esrc[slot] = sd.x;
    }
}

// ---------------- fused aggregation: wave per node, lane = head*16 + cg ----------------
// lean ILP-4 body, inline exp; TLP does the latency hiding. 128-thread blocks.
__global__ __launch_bounds__(128) void fused_agg_kernel(
    const unsigned short* __restrict__ h2,      // [N,256] bf16
    const float* __restrict__ a_src,            // [N,4]
    const float* __restrict__ a_dst,            // [N,4]
    const int*   __restrict__ offsets,          // [N+1]
    const int*   __restrict__ esrc,             // [E]
    const float* __restrict__ bias,             // [64]
    float*       __restrict__ out,              // [N,64]
    int n)
{
    int i    = (int)((blockIdx.x * blockDim.x + threadIdx.x) >> 6);
    int lane = threadIdx.x & 63;
    if (i >= n) return;
    const int h  = lane >> 4;
    const int cg = lane & 15;

    const float ad = a_dst[(size_t)i * HEADS + h];
    const unsigned short* h2p = h2 + lane * 4;

    float acc0, acc1, acc2, acc3, l;
    {   // self-loop
        float as = a_src[(size_t)i * HEADS + h];
        float e = as + ad; e = e > 0.f ? e : NEG_SLOPE * e;
        float p = __expf(e);
        ushort4 v = *(const ushort4*)(h2p + (size_t)i * 256);
        l = p;
        acc0 = p * bf2f(v.x);
        acc1 = p * bf2f(v.y);
        acc2 = p * bf2f(v.z);
        acc3 = p * bf2f(v.w);
    }

#define EDGE_BODY(S, AS)                                                     \
    {                                                                        \
        float e_ = (AS) + ad; e_ = e_ > 0.f ? e_ : NEG_SLOPE * e_;           \
        float p_ = __expf(e_);                                               \
        ushort4 v_ = *(const ushort4*)(h2p + (size_t)(S) * 256);             \
        l += p_;                                                             \
        acc0 = fmaf(p_, bf2f(v_.x), acc0);                                   \
        acc1 = fmaf(p_, bf2f(v_.y), acc1);                                   \
        acc2 = fmaf(p_, bf2f(v_.z), acc2);                                   \
        acc3 = fmaf(p_, bf2f(v_.w), acc3);                                   \
    }

    int beg = offsets[i], end = offsets[i + 1];
    int j = beg;
    // align to 4 for int4 esrc loads
    for (; j < end && (j & 3); ++j) {
        int s = esrc[j];
        float as = a_src[(size_t)s * HEADS + h];
        EDGE_BODY(s, as);
    }
    // batches of 4: one int4 load -> 4 a_src + 4 h2 gathers in flight
    for (; j + 3 < end; j += 4) {
        int4 ea = *(const int4*)(esrc + j);
        float as0 = a_src[(size_t)ea.x * HEADS + h];
        float as1 = a_src[(size_t)ea.y * HEADS + h];
        float as2 = a_src[(size_t)ea.z * HEADS + h];
        float as3 = a_src[(size_t)ea.w * HEADS + h];
        ushort4 v0 = *(const ushort4*)(h2p + (size_t)ea.x * 256);
        ushort4 v1 = *(const ushort4*)(h2p + (size_t)ea.y * 256);
        ushort4 v2 = *(const ushort4*)(h2p + (size_t)ea.z * 256);
        ushort4 v3 = *(const ushort4*)(h2p + (size_t)ea.w * 256);
        float e0 = as0 + ad; e0 = e0 > 0.f ? e0 : NEG_SLOPE * e0; float p0 = __expf(e0);
        float e1 = as1 + ad; e1 = e1 > 0.f ? e1 : NEG_SLOPE * e1; float p1 = __expf(e1);
        float e2 = as2 + ad; e2 = e2 > 0.f ? e2 : NEG_SLOPE * e2; float p2 = __expf(e2);
        float e3 = as3 + ad; e3 = e3 > 0.f ? e3 : NEG_SLOPE * e3; float p3 = __expf(e3);
        l += (p0 + p1) + (p2 + p3);
        acc0 = fmaf(p0, bf2f(v0.x), acc0);
        acc1 = fmaf(p0, bf2f(v0.y), acc1);
        acc2 = fmaf(p0, bf2f(v0.z), acc2);
        acc3 = fmaf(p0, bf2f(v0.w), acc3);
        acc0 = fmaf(p1, bf2f(v1.x), acc0);
        acc1 = fmaf(p1, bf2f(v1.y), acc1);
        acc2 = fmaf(p1, bf2f(v1.z), acc2);
        acc3 = fmaf(p1, bf2f(v1.w), acc3);
        acc0 = fmaf(p2, bf2f(v2.x), acc0);
        acc1 = fmaf(p2, bf2f(v2.y), acc1);
        acc2 = fmaf(p2, bf2f(v2.z), acc2);
        acc3 = fmaf(p2, bf2f(v2.w), acc3);
        acc0 = fmaf(p3, bf2f(v3.x), acc0);
        acc1 = fmaf(p3, bf2f(v3.y), acc1);
        acc2 = fmaf(p3, bf2f(v3.z), acc2);
        acc3 = fmaf(p3, bf2f(v3.w), acc3);
    }
    for (; j < end; ++j) {
        int s = esrc[j];
        float as = a_src[(size_t)s * HEADS + h];
        EDGE_BODY(s, as);
    }
#undef EDGE_BODY

    float inv = 1.f / (l + 1e-16f);
    float r0 = acc0 * inv, r1 = acc1 * inv, r2 = acc2 * inv, r3 = acc3 * inv;

    r0 += __shfl_xor(r0, 16, 64); r0 += __shfl_xor(r0, 32, 64);
    r1 += __shfl_xor(r1, 16, 64); r1 += __shfl_xor(r1, 32, 64);
    r2 += __shfl_xor(r2, 16, 64); r2 += __shfl_xor(r2, 32, 64);
    r3 += __shfl_xor(r3, 16, 64); r3 += __shfl_xor(r3, 32, 64);

    if (lane < 16) {
        float4 b4 = *(const float4*)(bias + cg * 4);
        float4 o;
        o.x = 0.25f * r0 + b4.x;
        o.y = 0.25f * r1 + b4.y;
        o.z = 0.25f * r2 + b4.z;
        o.w = 0.25f * r3 + b4.w;
        *(float4*)(out + (size_t)i * OUTC + cg * 4) = o;
    }
}

extern "C" void kernel_launch(void* const* d_in, const int* in_sizes, int n_in,
                              void* d_out, int out_size, void* d_ws, size_t ws_size,
                              hipStream_t stream)
{
    (void)n_in; (void)out_size; (void)ws_size;
    const float* x       = (const float*)d_in[0];
    const int*   edge    = (const int*)d_in[1];
    const float* W       = (const float*)d_in[2];
    const float* att_src = (const float*)d_in[3];
    const float* att_dst = (const float*)d_in[4];
    const float* bias    = (const float*)d_in[5];
    float* out = (float*)d_out;

    const int N = in_sizes[0] / INC;
    const int E = in_sizes[1] / 2;
    const int* srcA = edge;
    const int* dstA = edge + E;
    const int nbuck = (N + 255) / 256;          // 196
    const int nbA   = (E + EPB_A - 1) / EPB_A;  // 391

    char* ws = (char*)d_ws;
    unsigned short* h2 = (unsigned short*)ws; ws += (size_t)N * (HEADS * OUTC) * sizeof(unsigned short);
    unsigned short* Wt = (unsigned short*)ws; ws += (size_t)256 * 256 * sizeof(unsigned short);
    float* a_src  = (float*)ws; ws += (size_t)N * HEADS * sizeof(float);
    float* a_dst  = (float*)ws; ws += (size_t)N * HEADS * sizeof(float);
    int* offsets  = (int*)ws;   ws += (size_t)(N + 1) * sizeof(int) + 12;
    int* btail    = (int*)ws;   ws += (size_t)256 * sizeof(int);
    int2* bucketbuf = (int2*)ws; ws += (size_t)nbuck * CAP * sizeof(int2);
    int* esrc     = (int*)ws;   ws += (size_t)E * sizeof(int);

    wt_zero_kernel<<<256, 256, 0, stream>>>(W, Wt, btail, nbuck);

    gemm_passA<<<nbA + (N + 63) / 64, 256, 0, stream>>>(
        x, Wt, att_src, att_dst, h2, a_src, a_dst, N,
        srcA, dstA, btail, bucketbuf, E, nbA);

    passB_kernel<<<nbuck, 256, 0, stream>>>(bucketbuf, btail, offsets, esrc, N, E);

    fused_agg_kernel<<<(N + 1) / 2, 128, 0, stream>>>(h2, a_src, a_dst, offsets, esrc,
                                                      bias, out, N);
}